// Round 15
// baseline (256.406 us; speedup 1.0000x reference)
//
#include <hip/hip_runtime.h>
#include <hip/hip_bf16.h>

typedef __bf16 bf16;
typedef __attribute__((ext_vector_type(8))) __bf16 bf16x8;
typedef __attribute__((ext_vector_type(4))) __bf16 bf16x4;
typedef __attribute__((ext_vector_type(4))) float f32x4;
typedef __attribute__((ext_vector_type(16))) float f32x16;
typedef __attribute__((ext_vector_type(4))) int int4v;

#define TSEQ 2048
#define DMODEL 1024
#define NHEAD 16
#define DKH 64
#define BATCH 2
#define NQKV 3072

// async global->LDS, 16B per lane; LDS dest = wave-uniform base + lane*16
typedef __attribute__((address_space(1))) const void gv_t;
typedef __attribute__((address_space(3))) void sv_t;
__device__ __forceinline__ void gll16(const bf16* g, bf16* s) {
    __builtin_amdgcn_global_load_lds((gv_t*)g, (sv_t*)s, 16, 0, 0);
}
// counted vmcnt wait (lgkmcnt=15, expcnt=7 untouched). __syncthreads does NOT
// drain DMA vmcnt on this toolchain -> explicit wait required.
#define WAIT_VM(n) __builtin_amdgcn_s_waitcnt(0x0F70 | (n))

// v_cvt_pk_bf16_f32: D.lo = bf16(s0), D.hi = bf16(s1)
__device__ __forceinline__ unsigned cvtpk(float lo, float hi) {
    unsigned d;
    asm("v_cvt_pk_bf16_f32 %0, %1, %2" : "=v"(d) : "v"(lo), "v"(hi));
    return d;
}

// ------------------------------------------------------- fused prep kernel
#define PREP_CONV 4096   // NX / (256*4)
#define PREP_TW   4096
#define PREP_GRID (PREP_CONV + PREP_TW + 12)
__global__ __launch_bounds__(256) void prep(
    const float* __restrict__ x,
    const float* __restrict__ Wq, const float* __restrict__ Wk,
    const float* __restrict__ Wv, const float* __restrict__ Wo,
    const float* __restrict__ bq, const float* __restrict__ bk,
    const float* __restrict__ bv,
    bf16* __restrict__ xb, bf16* __restrict__ WT, float* __restrict__ biasO)
{
    __shared__ float t[32][33];
    int bid = blockIdx.x;
    const int tid = threadIdx.x;
    if (bid < PREP_CONV) {                       // ---- convert
        int i = (bid * 256 + tid) * 4;
        f32x4 v = *(const f32x4*)(x + i);
        bf16x4 o;
#pragma unroll
        for (int j = 0; j < 4; ++j) o[j] = (bf16)v[j];
        *(bf16x4*)(xb + i) = o;
        return;
    }
    bid -= PREP_CONV;
    if (bid < PREP_TW) {                         // ---- transpose W (32x32 tile)
        int z = bid >> 10;
        int by = ((bid >> 5) & 31) * 32, bx = (bid & 31) * 32;
        const float* W = z == 0 ? Wq : z == 1 ? Wk : z == 2 ? Wv : Wo;
        bf16* T = WT + (size_t)z * DMODEL * DMODEL;
        int tx = tid & 31, ty = tid >> 5;
#pragma unroll
        for (int i = 0; i < 4; ++i)
            t[ty + i * 8][tx] = W[(size_t)(by + ty + i * 8) * DMODEL + bx + tx];
        __syncthreads();
#pragma unroll
        for (int i = 0; i < 4; ++i)
            T[(size_t)(bx + ty + i * 8) * DMODEL + by + tx] = (bf16)t[tx][ty + i * 8];
        return;
    }
    bid -= PREP_TW;
    int i = bid * 256 + tid;                     // ---- bias concat, 0..3071
    float v = i < 1024 ? bq[i] : i < 2048 ? bk[i - 1024] : bv[i - 2048];
    biasO[i] = v;
}

// ---------------------------------------------------------------- GEMM + bias
// (r11 body, proven) BK=64, 2-buffer, XOR-swizzled LDS tiles, XCD-chunked
// mapping. FUSE_VT: n0>=2048 writes V-part transposed to VT.
template <typename OutT, int NW_N, bool FUSE_VT>
__global__ __launch_bounds__(256) void gemm_bias_kernel(
    const bf16* __restrict__ A, const bf16* __restrict__ BT,
    const float* __restrict__ bias, OutT* __restrict__ C, int ldc,
    bf16* __restrict__ VT)
{
    constexpr int BN    = NW_N * 64;
    constexpr int MW    = 4 / NW_N;
    constexpr int WROWS = 128 / MW;
    constexpr int FM    = WROWS / 16;
    constexpr int BK    = 64;
    constexpr int ASZ   = 128 * BK;
    constexpr int BSZ   = BN * BK;
    constexpr int BNP   = BN + 4;
    constexpr int TST   = 136;
    constexpr int EPI   = sizeof(OutT) == 2 ? (FUSE_VT ? 128 * TST : 128 * BN)
                                            : 64 * BNP * 2;
    constexpr int STG   = 2 * ASZ + 2 * BSZ;
    constexpr int SMEM  = STG > EPI ? STG : EPI;
    __shared__ bf16 smem[SMEM];
    bf16* As0 = smem;
    bf16* Bs0 = smem + 2 * ASZ;

    const int tid = threadIdx.x;
    const int ln = tid & 63, wave = tid >> 6;
    const int wm = NW_N == 2 ? (wave >> 1) : wave;
    const int wn = NW_N == 2 ? (wave & 1) : 0;
    const int lr = ln & 15, quad = ln >> 4;

    constexpr int NBX = (NW_N == 2) ? 24 : 16;
    constexpr int CH  = (NW_N == 2) ? 96 : 64;
    const int wg  = blockIdx.x;
    const int lin = (wg & 7) * CH + (wg >> 3);
    const int m0  = (lin / NBX) * 128, n0 = (lin % NBX) * BN;

    f32x4 acc[FM][4] = {};

    const int srow = ln >> 3;
    const int scol = ((ln & 7) ^ srow) * 8;
    const bf16* Ag = A + (size_t)(m0 + wave * 32 + srow) * DMODEL + scol;
    const bf16* Bg = BT + (size_t)(n0 + (NW_N == 2 ? wave * 32 : wave * 16) + srow) * DMODEL + scol;

    auto stage = [&](int buf, int kk) {
        bf16* AsW = As0 + buf * ASZ + wave * (32 * BK);
#pragma unroll
        for (int l = 0; l < 4; ++l)
            gll16(Ag + (size_t)(l * 8) * DMODEL + kk, AsW + l * 8 * BK);
        if constexpr (NW_N == 2) {
            bf16* BsW = Bs0 + buf * BSZ + wave * (32 * BK);
#pragma unroll
            for (int l = 0; l < 4; ++l)
                gll16(Bg + (size_t)(l * 8) * DMODEL + kk, BsW + l * 8 * BK);
        } else {
            bf16* BsW = Bs0 + buf * BSZ + wave * (16 * BK);
#pragma unroll
            for (int l = 0; l < 2; ++l)
                gll16(Bg + (size_t)(l * 8) * DMODEL + kk, BsW + l * 8 * BK);
        }
    };

    constexpr int NT = DMODEL / BK;
    stage(0, 0);
    WAIT_VM(0);
    __syncthreads();
    const int swr = lr & 7;
    for (int kt = 0; kt < NT; ++kt) {
        if (kt + 1 < NT) stage((kt + 1) & 1, (kt + 1) * BK);
        const bf16* AsB = As0 + (kt & 1) * ASZ;
        const bf16* BsB = Bs0 + (kt & 1) * BSZ;
#pragma unroll
        for (int k2 = 0; k2 < 2; ++k2) {
            bf16x8 af[FM], bfr[4];
#pragma unroll
            for (int i = 0; i < FM; ++i)
                af[i] = *(const bf16x8*)(AsB + (wm * WROWS + i * 16 + lr) * BK +
                                         (((k2 * 4 + quad) ^ swr) * 8));
#pragma unroll
            for (int j = 0; j < 4; ++j)
                bfr[j] = *(const bf16x8*)(BsB + (wn * 64 + j * 16 + lr) * BK +
                                          (((k2 * 4 + quad) ^ swr) * 8));
#pragma unroll
            for (int i = 0; i < FM; ++i)
#pragma unroll
                for (int j = 0; j < 4; ++j)
                    acc[i][j] = __builtin_amdgcn_mfma_f32_16x16x32_bf16(
                        af[i], bfr[j], acc[i][j], 0, 0, 0);
        }
        WAIT_VM(0);
        __syncthreads();
    }

    if constexpr (sizeof(OutT) == 2) {
        if (FUSE_VT && n0 >= 2048) {
            bf16* Cs = smem;
#pragma unroll
            for (int j = 0; j < 4; ++j) {
                int nl = wn * 64 + j * 16 + lr;
                float bv = bias[n0 + nl];
#pragma unroll
                for (int i = 0; i < FM; ++i) {
                    int ml = wm * WROWS + i * 16 + quad * 4;
#pragma unroll
                    for (int r = 0; r < 4; ++r)
                        Cs[nl * TST + ml + r] = (bf16)(acc[i][j][r] + bv);
                }
            }
            __syncthreads();
            const int bb = m0 >> 11;
            const int tloc = m0 & 2047;
#pragma unroll
            for (int pp = 0; pp < 8; ++pp) {
                int dl = pp * 16 + (tid >> 4);
                int t0 = (tid & 15) * 8;
                bf16x8 v = *(const bf16x8*)(Cs + dl * TST + t0);
                *(bf16x8*)(VT + (size_t)(bb * 1024 + (n0 - 2048) + dl) * TSEQ +
                           tloc + t0) = v;
            }
            return;
        }
        bf16* Cs = smem;
#pragma unroll
        for (int j = 0; j < 4; ++j) {
            int nl = wn * 64 + j * 16 + lr;
            float bv = bias[n0 + nl];
#pragma unroll
            for (int i = 0; i < FM; ++i) {
                int ml = wm * WROWS + i * 16 + quad * 4;
#pragma unroll
                for (int r = 0; r < 4; ++r)
                    Cs[(ml + r) * BN + nl] = (bf16)(acc[i][j][r] + bv);
            }
        }
        __syncthreads();
        constexpr int LPR = BN / 8;
        constexpr int RPP = 256 / LPR;
        const int rr = tid / LPR, cc = (tid % LPR) * 8;
#pragma unroll
        for (int pp = 0; pp < 128 / RPP; ++pp) {
            int row = pp * RPP + rr;
            *(bf16x8*)(C + (size_t)(m0 + row) * ldc + n0 + cc) =
                *(const bf16x8*)(Cs + row * BN + cc);
        }
    } else {
        float* Cf = (float*)smem;
#pragma unroll
        for (int half = 0; half < 2; ++half) {
            if (((wm * WROWS) >> 6) == half) {
#pragma unroll
                for (int j = 0; j < 4; ++j) {
                    int nl = wn * 64 + j * 16 + lr;
                    float bv = bias[n0 + nl];
#pragma unroll
                    for (int i = 0; i < FM; ++i) {
                        int ml = wm * WROWS + i * 16 + quad * 4 - half * 64;
#pragma unroll
                        for (int r = 0; r < 4; ++r)
                            Cf[(ml + r) * BNP + nl] = acc[i][j][r] + bv;
                    }
                }
            }
            __syncthreads();
            constexpr int LPR = BN / 4;
            constexpr int RPP = 256 / LPR;
            const int rr = tid / LPR, cc = (tid % LPR) * 4;
#pragma unroll
            for (int pp = 0; pp < 64 / RPP; ++pp) {
                int row = pp * RPP + rr;
                *(f32x4*)(C + (size_t)(m0 + half * 64 + row) * ldc + n0 + cc) =
                    *(const f32x4*)(Cf + row * BNP + cc);
            }
            __syncthreads();
        }
    }
}

// ---------------------------------------------------------------- flash attn
// 8-WAVE PARITY-GROUP version of the r11 kernel: 512 blocks x 512 threads.
// Two 4-wave groups process chunk PARITIES concurrently (group g = chunks
// with c%2==g), each staging its own parity into its own pair of the 4 LDS
// buffers. K/V fetched ONCE per block (unlike r12's split-K: no HBM partial
// writes, no extra fetch). Fixed-max softmax => partials are linear; groups
// merge through LDS in a 3-round epilogue. Occupancy: 2 blocks/CU x 8 waves
// = 16 waves/CU = 4 waves/SIMD (vs r11's 2) -> the serial QK->softmax->PV
// chain of one wave overlaps with 3 others per SIMD.
// Per-group structure = r11 verbatim: phase1 (c<=p) waves wl{0,1}=A rows,
// wl{2,3}=B rows, full 64-key; phase2 (c>p) all 4 waves key-split B.
template <int KTN, bool MASKED>
__device__ __forceinline__ void tile_step(
    int kt0, int kc, int qabs,
    const bf16* __restrict__ Ksb, const bf16* __restrict__ Vsb,
    const bf16x8 qf[4], f32x16 oacc[2], float& lrow,
    int ln31, int hi, int sw)
{
    f32x16 st[KTN] = {};
    __builtin_amdgcn_s_setprio(1);
#pragma unroll
    for (int t = 0; t < KTN; ++t)
#pragma unroll
        for (int ks = 0; ks < 4; ++ks) {
            const bf16x8 ka = *(const bf16x8*)(
                Ksb + (ln31 + (kt0 + t) * 32) * 64 + (((2 * ks + hi) ^ sw) * 8));
            st[t] = __builtin_amdgcn_mfma_f32_32x32x16_bf16(ka, qf[ks], st[t], 0, 0, 0);
        }
    __builtin_amdgcn_s_setprio(0);

    const float scale2 = 0.18033688f; // 0.125 * log2(e)
    float rs = 0.f;
#pragma unroll
    for (int t = 0; t < KTN; ++t)
#pragma unroll
        for (int r = 0; r < 16; ++r) {
            float p = exp2f(fmaf(st[t][r], scale2, -24.0f));
            if (MASKED &&
                (kc + (kt0 + t) * 32 + (r & 3) + 8 * (r >> 2) + 4 * hi > qabs))
                p = 0.f;
            rs += p;
            st[t][r] = p;
        }
    rs += __shfl_xor(rs, 32);
    lrow += rs;

    __builtin_amdgcn_s_setprio(1);
#pragma unroll
    for (int t = 0; t < KTN; ++t)
#pragma unroll
        for (int s2 = 0; s2 < 2; ++s2) {
            const int bb = s2 * 8;
            unsigned c01 = cvtpk(st[t][bb + 0], st[t][bb + 1]);
            unsigned c23 = cvtpk(st[t][bb + 2], st[t][bb + 3]);
            unsigned c45 = cvtpk(st[t][bb + 4], st[t][bb + 5]);
            unsigned c67 = cvtpk(st[t][bb + 6], st[t][bb + 7]);
            asm("v_permlane32_swap_b32 %0, %1" : "+v"(c01), "+v"(c45));
            asm("v_permlane32_swap_b32 %0, %1" : "+v"(c23), "+v"(c67));
            int4v pw;
            pw[0] = (int)c01; pw[1] = (int)c23; pw[2] = (int)c45; pw[3] = (int)c67;
            const bf16x8 pa = __builtin_bit_cast(bf16x8, pw);
            const int ksg = (kt0 + t) * 2 + s2;
#pragma unroll
            for (int dblk = 0; dblk < 2; ++dblk) {
                const bf16x8 vb = *(const bf16x8*)(
                    Vsb + (dblk * 32 + ln31) * 64 + (((2 * ksg + hi) ^ sw) * 8));
                oacc[dblk] = __builtin_amdgcn_mfma_f32_32x32x16_bf16(
                    pa, vb, oacc[dblk], 0, 0, 0);
            }
        }
    __builtin_amdgcn_s_setprio(0);
}

__global__ __launch_bounds__(512, 4) void flash_attn(
    const bf16* __restrict__ QKV, const bf16* __restrict__ VT,
    bf16* __restrict__ O)
{
    __shared__ bf16 Ks[4][64 * 64];
    __shared__ bf16 Vs[4][64 * 64];
    const int tid = threadIdx.x;
    const int ln = tid & 63, w = tid >> 6;       // 8 waves
    const int grp = w >> 2, wl = w & 3;          // 2 parity groups x 4 waves
    const int ln31 = ln & 31, hi = ln >> 5, sw = ln & 7;
    const int wg = blockIdx.x;
    const int g = wg & 31, p = wg >> 5;          // g = 2h+b -> fixed XCD per (b,h)
    const int h = g >> 1, b = g & 1;
    const int q0A = p * 64, q0B = (31 - p) * 64;

    const bf16* Qb = QKV + (size_t)b * TSEQ * NQKV + h * DKH;
    const bf16* Kb = Qb + 1024;
    const bf16* VTb = VT + (size_t)(b * NHEAD + h) * DKH * TSEQ;

    const int q1 = (wl < 2 ? q0A : q0B) + (wl & 1) * 32 + ln31;
    const int q2 = q0B + (wl & 1) * 32 + ln31;

    bf16x8 qf1[4], qf2[4];
#pragma unroll
    for (int ks = 0; ks < 4; ++ks) {
        qf1[ks] = *(const bf16x8*)(Qb + (size_t)q1 * NQKV + ks * 16 + hi * 8);
        qf2[ks] = *(const bf16x8*)(Qb + (size_t)q2 * NQKV + ks * 16 + hi * 8);
    }
    WAIT_VM(0);   // qf complete before any DMA -> clean in-loop counts

    // staging within group: wl{0,1} -> K row-halves, wl{2,3} -> V row-halves
    const int srow = (wl & 1) * 32 + (ln >> 3);
    const int scol = ((ln & 7) ^ ((ln >> 3) & 7)) * 8;
    const bool stK = (wl < 2);
    auto stage = [&](int buf, int kc) {
        if (stK) {
            const bf16* g2 = Kb + (size_t)(kc + srow) * NQKV + scol;
            bf16* s = &Ks[buf][(wl & 1) * 32 * 64];
#pragma unroll
            for (int l = 0; l < 4; ++l)
                gll16(g2 + (size_t)(l * 8) * NQKV, s + l * 8 * 64);
        } else {
            const bf16* g2 = VTb + (size_t)srow * TSEQ + kc + scol;
            bf16* s = &Vs[buf][(wl & 1) * 32 * 64];
#pragma unroll
            for (int l = 0; l < 4; ++l)
                gll16(g2 + (size_t)(l * 8) * TSEQ, s + l * 8 * 64);
        }
    };

    f32x16 oacc1[2] = {}, oacc2[2] = {};
    float l1 = 0.f, l2 = 0.f;

    const int nld = 32 - p;    // shared stream length (17..32)

    auto do_chunk = [&](int c) {
        const int kc = c * 64;
        const bf16* K = Ks[c & 3];
        const bf16* V = Vs[c & 3];
        if (c <= p) {            // phase1: full 64-key chunk, own tile
            if (wl < 2 && c == p)
                tile_step<2, true >(0, kc, q1, K, V, qf1, oacc1, l1, ln31, hi, sw);
            else
                tile_step<2, false>(0, kc, q1, K, V, qf1, oacc1, l1, ln31, hi, sw);
        } else {                 // phase2: all 4 group-waves on B, key-split
            const int kt0 = wl >> 1;
            if (c == nld - 1)
                tile_step<1, true >(kt0, kc, q2, K, V, qf2, oacc2, l2, ln31, hi, sw);
            else
                tile_step<1, false>(kt0, kc, q2, K, V, qf2, oacc2, l2, ln31, hi, sw);
        }
    };

    // group g owns chunks with parity g; 2 buffers per parity (c&3)
    if (grp == 0) stage(0, 0);
    else          stage(1, 64);              // nld >= 17 always
    for (int c0 = 0; c0 < nld; c0 += 2) {
        const int c = c0 + grp;              // my group's chunk this iteration
        WAIT_VM(0);                          // my prefetched chunk landed
        __syncthreads();                     // both groups' buffers visible
        const int cn = c + 2;
        if (cn < nld) stage(cn & 3, cn * 64);
        if (c < nld) do_chunk(c);
    }
    WAIT_VM(0);
    __syncthreads();                         // before epilogue LDS reuse

    // ---- epilogue: 3-round LDS merge of the two groups' linear partials.
    // Contributors per B row-group rg: (g,wl=rg):oacc2  and
    // (g,wl=rg+2):oacc1+oacc2, g=0,1. A row-group rg: (g,wl=rg):oacc1.
    float* base = (float*)&Ks[0][0];
    float* AO  = base;                  // [2][32*64] f32 = 16KB (Ks bufs 0-1)
    float* BO  = base + 4096;           // 16KB (Ks bufs 2-3)
    float* BO2 = (float*)&Vs[0][0];     // 16KB (Vs bufs 0-1)
    float* AL  = (float*)&Vs[2][0];     // 64 f32 (in Vs buf 2)
    float* BL  = AL + 64;
    float* BL2 = AL + 128;
    const int rg = wl & 1;

    // R1: group 1 deposits its partials
    if (grp == 1) {
        if (wl < 2) {
            float* dA = AO + rg * 2048;
            float* dB = BO2 + rg * 2048;
#pragma unroll
            for (int dblk = 0; dblk < 2; ++dblk)
#pragma unroll
                for (int r = 0; r < 16; ++r) {
                    int q = (r & 3) + 8 * (r >> 2) + 4 * hi;
                    dA[q * 64 + dblk * 32 + ln31] = oacc1[dblk][r];
                    dB[q * 64 + dblk * 32 + ln31] = oacc2[dblk][r];
                }
            if (ln < 32) { AL[rg * 32 + ln] = l1; BL2[rg * 32 + ln] = l2; }
        } else {
            float* dB = BO + rg * 2048;
#pragma unroll
            for (int dblk = 0; dblk < 2; ++dblk)
#pragma unroll
                for (int r = 0; r < 16; ++r) {
                    int q = (r & 3) + 8 * (r >> 2) + 4 * hi;
                    dB[q * 64 + dblk * 32 + ln31] = oacc1[dblk][r] + oacc2[dblk][r];
                }
            if (ln < 32) BL[rg * 32 + ln] = l1 + l2;
        }
    }
    __syncthreads();
    // R2: group 0 merges; wl<2 write final A rows and add B shares
    if (grp == 0) {
        if (wl < 2) {
            float* dB = BO2 + rg * 2048;
#pragma unroll
            for (int dblk = 0; dblk < 2; ++dblk)
#pragma unroll
                for (int r = 0; r < 16; ++r) {
                    int q = (r & 3) + 8 * (r >> 2) + 4 * hi;
                    dB[q * 64 + dblk * 32 + ln31] += oacc2[dblk][r];
                }
            if (ln < 32) BL2[rg * 32 + ln] += l2;
            const float* sA = AO + rg * 2048;
            float lt = l1 + AL[rg * 32 + ln31];
            const int qs = q0A + rg * 32;
#pragma unroll
            for (int r = 0; r < 16; ++r) {
                const int crow = (r & 3) + 8 * (r >> 2) + 4 * hi;
                const float inv = 1.0f / __shfl(lt, crow);
                const int row = qs + crow;
#pragma unroll
                for (int dblk = 0; dblk < 2; ++dblk)
                    O[(size_t)(b * TSEQ + row) * DMODEL + h * DKH + dblk * 32 + ln31] =
                        (bf16)((oacc1[dblk][r] +
                                sA[crow * 64 + dblk * 32 + ln31]) * inv);
            }
        } else {
            float* dB = BO + rg * 2048;
#pragma unroll
            for (int dblk = 0; dblk < 2; ++dblk)
#pragma unroll
                for (int r = 0; r < 16; ++r) {
                    int q = (r & 3) + 8 * (r >> 2) + 4 * hi;
                    dB[q * 64 + dblk * 32 + ln31] += oacc1[dblk][r] + oacc2[dblk][r];
                }
            if (ln < 32) BL[rg * 32 + ln] += l1 + l2;
        }
    }
    __syncthreads();
    // R3: group 0 wl>=2 write final B rows
    if (grp == 0 && wl >= 2) {
        const float* sB  = BO + rg * 2048;
        const float* sB2 = BO2 + rg * 2048;
        float lt = BL[rg * 32 + ln31] + BL2[rg * 32 + ln31];
        const int qs = q0B + rg * 32;
#pragma unroll
        for (int r = 0; r < 16; ++r) {
            const int crow = (r & 3) + 8 * (r >> 2) + 4 * hi;
            const float inv = 1.0f / __shfl(lt, crow);
            const int row = qs + crow;
#pragma unroll
            for (int dblk = 0; dblk < 2; ++dblk) {
                const int idx = crow * 64 + dblk * 32 + ln31;
                O[(size_t)(b * TSEQ + row) * DMODEL + h * DKH + dblk * 32 + ln31] =
                    (bf16)((sB[idx] + sB2[idx]) * inv);
            }
        }
    }
}

// ---------------------------------------------------------------- launch
extern "C" void kernel_launch(void* const* d_in, const int* in_sizes, int n_in,
                              void* d_out, int out_size, void* d_ws, size_t ws_size,
                              hipStream_t stream)
{
    const float* x  = (const float*)d_in[0];
    const float* Wq = (const float*)d_in[2];
    const float* bq = (const float*)d_in[3];
    const float* Wk = (const float*)d_in[4];
    const float* bk = (const float*)d_in[5];
    const float* Wv = (const float*)d_in[6];
    const float* bv = (const float*)d_in[7];
    const float* Wo = (const float*)d_in[8];
    const float* bo = (const float*)d_in[9];

    char* ws = (char*)d_ws;
    bf16* xb   = (bf16*)(ws);                   // 8 MB
    bf16* QKV  = (bf16*)(ws + (8u  << 20));     // 24 MB [4096][3072] (V third unused)
    bf16* VT   = (bf16*)(ws + (32u << 20));     // 8 MB, written by QKV-GEMM V blocks
    bf16* O    = (bf16*)(ws + (40u << 20));     // 8 MB
    bf16* WT   = (bf16*)(ws + (48u << 20));     // 8 MB
    float* wsBias = (float*)O;                  // 12 KB, consumed before flash writes O

    prep<<<PREP_GRID, 256, 0, stream>>>(x, Wq, Wk, Wv, Wo, bq, bk, bv,
                                        xb, WT, wsBias);

    gemm_bias_kernel<bf16, 2, true><<<768, 256, 0, stream>>>(
        xb, WT, wsBias, QKV, NQKV, VT);

    flash_attn<<<512, 512, 0, stream>>>(QKV, VT, O);

    gemm_bias_kernel<float, 1, false><<<512, 256, 0, stream>>>(
        O, WT + 3u * (1u << 20), bo, (float*)d_out, DMODEL, nullptr);
}

// Round 16
// 208.336 us; speedup vs baseline: 1.2307x; 1.2307x over previous
//
#include <hip/hip_runtime.h>
#include <hip/hip_bf16.h>

typedef __bf16 bf16;
typedef __attribute__((ext_vector_type(8))) __bf16 bf16x8;
typedef __attribute__((ext_vector_type(4))) __bf16 bf16x4;
typedef __attribute__((ext_vector_type(4))) float f32x4;
typedef __attribute__((ext_vector_type(16))) float f32x16;
typedef __attribute__((ext_vector_type(4))) int int4v;

#define TSEQ 2048
#define DMODEL 1024
#define NHEAD 16
#define DKH 64
#define BATCH 2
#define NQKV 3072

// async global->LDS, 16B per lane; LDS dest = wave-uniform base + lane*16
typedef __attribute__((address_space(1))) const void gv_t;
typedef __attribute__((address_space(3))) void sv_t;
__device__ __forceinline__ void gll16(const bf16* g, bf16* s) {
    __builtin_amdgcn_global_load_lds((gv_t*)g, (sv_t*)s, 16, 0, 0);
}
// counted vmcnt wait (lgkmcnt=15, expcnt=7 untouched). __syncthreads does NOT
// drain DMA vmcnt on this toolchain -> explicit wait required.
#define WAIT_VM(n) __builtin_amdgcn_s_waitcnt(0x0F70 | (n))

// v_cvt_pk_bf16_f32: D.lo = bf16(s0), D.hi = bf16(s1)
__device__ __forceinline__ unsigned cvtpk(float lo, float hi) {
    unsigned d;
    asm("v_cvt_pk_bf16_f32 %0, %1, %2" : "=v"(d) : "v"(lo), "v"(hi));
    return d;
}

// ------------------------------------------------------- fused prep kernel
#define PREP_CONV 4096   // NX / (256*4)
#define PREP_TW   4096
#define PREP_GRID (PREP_CONV + PREP_TW + 12)
__global__ __launch_bounds__(256) void prep(
    const float* __restrict__ x,
    const float* __restrict__ Wq, const float* __restrict__ Wk,
    const float* __restrict__ Wv, const float* __restrict__ Wo,
    const float* __restrict__ bq, const float* __restrict__ bk,
    const float* __restrict__ bv,
    bf16* __restrict__ xb, bf16* __restrict__ WT, float* __restrict__ biasO)
{
    __shared__ float t[32][33];
    int bid = blockIdx.x;
    const int tid = threadIdx.x;
    if (bid < PREP_CONV) {                       // ---- convert
        int i = (bid * 256 + tid) * 4;
        f32x4 v = *(const f32x4*)(x + i);
        bf16x4 o;
#pragma unroll
        for (int j = 0; j < 4; ++j) o[j] = (bf16)v[j];
        *(bf16x4*)(xb + i) = o;
        return;
    }
    bid -= PREP_CONV;
    if (bid < PREP_TW) {                         // ---- transpose W (32x32 tile)
        int z = bid >> 10;
        int by = ((bid >> 5) & 31) * 32, bx = (bid & 31) * 32;
        const float* W = z == 0 ? Wq : z == 1 ? Wk : z == 2 ? Wv : Wo;
        bf16* T = WT + (size_t)z * DMODEL * DMODEL;
        int tx = tid & 31, ty = tid >> 5;
#pragma unroll
        for (int i = 0; i < 4; ++i)
            t[ty + i * 8][tx] = W[(size_t)(by + ty + i * 8) * DMODEL + bx + tx];
        __syncthreads();
#pragma unroll
        for (int i = 0; i < 4; ++i)
            T[(size_t)(bx + ty + i * 8) * DMODEL + by + tx] = (bf16)t[tx][ty + i * 8];
        return;
    }
    bid -= PREP_TW;
    int i = bid * 256 + tid;                     // ---- bias concat, 0..3071
    float v = i < 1024 ? bq[i] : i < 2048 ? bk[i - 1024] : bv[i - 2048];
    biasO[i] = v;
}

// ---------------------------------------------------------------- GEMM + bias
// (r11 body, proven) BK=64, 2-buffer, XOR-swizzled LDS tiles, XCD-chunked
// mapping. FUSE_VT: n0>=2048 writes V-part transposed to VT.
template <typename OutT, int NW_N, bool FUSE_VT>
__global__ __launch_bounds__(256) void gemm_bias_kernel(
    const bf16* __restrict__ A, const bf16* __restrict__ BT,
    const float* __restrict__ bias, OutT* __restrict__ C, int ldc,
    bf16* __restrict__ VT)
{
    constexpr int BN    = NW_N * 64;
    constexpr int MW    = 4 / NW_N;
    constexpr int WROWS = 128 / MW;
    constexpr int FM    = WROWS / 16;
    constexpr int BK    = 64;
    constexpr int ASZ   = 128 * BK;
    constexpr int BSZ   = BN * BK;
    constexpr int BNP   = BN + 4;
    constexpr int TST   = 136;
    constexpr int EPI   = sizeof(OutT) == 2 ? (FUSE_VT ? 128 * TST : 128 * BN)
                                            : 64 * BNP * 2;
    constexpr int STG   = 2 * ASZ + 2 * BSZ;
    constexpr int SMEM  = STG > EPI ? STG : EPI;
    __shared__ bf16 smem[SMEM];
    bf16* As0 = smem;
    bf16* Bs0 = smem + 2 * ASZ;

    const int tid = threadIdx.x;
    const int ln = tid & 63, wave = tid >> 6;
    const int wm = NW_N == 2 ? (wave >> 1) : wave;
    const int wn = NW_N == 2 ? (wave & 1) : 0;
    const int lr = ln & 15, quad = ln >> 4;

    constexpr int NBX = (NW_N == 2) ? 24 : 16;
    constexpr int CH  = (NW_N == 2) ? 96 : 64;
    const int wg  = blockIdx.x;
    const int lin = (wg & 7) * CH + (wg >> 3);
    const int m0  = (lin / NBX) * 128, n0 = (lin % NBX) * BN;

    f32x4 acc[FM][4] = {};

    const int srow = ln >> 3;
    const int scol = ((ln & 7) ^ srow) * 8;
    const bf16* Ag = A + (size_t)(m0 + wave * 32 + srow) * DMODEL + scol;
    const bf16* Bg = BT + (size_t)(n0 + (NW_N == 2 ? wave * 32 : wave * 16) + srow) * DMODEL + scol;

    auto stage = [&](int buf, int kk) {
        bf16* AsW = As0 + buf * ASZ + wave * (32 * BK);
#pragma unroll
        for (int l = 0; l < 4; ++l)
            gll16(Ag + (size_t)(l * 8) * DMODEL + kk, AsW + l * 8 * BK);
        if constexpr (NW_N == 2) {
            bf16* BsW = Bs0 + buf * BSZ + wave * (32 * BK);
#pragma unroll
            for (int l = 0; l < 4; ++l)
                gll16(Bg + (size_t)(l * 8) * DMODEL + kk, BsW + l * 8 * BK);
        } else {
            bf16* BsW = Bs0 + buf * BSZ + wave * (16 * BK);
#pragma unroll
            for (int l = 0; l < 2; ++l)
                gll16(Bg + (size_t)(l * 8) * DMODEL + kk, BsW + l * 8 * BK);
        }
    };

    constexpr int NT = DMODEL / BK;
    stage(0, 0);
    WAIT_VM(0);
    __syncthreads();
    const int swr = lr & 7;
    for (int kt = 0; kt < NT; ++kt) {
        if (kt + 1 < NT) stage((kt + 1) & 1, (kt + 1) * BK);
        const bf16* AsB = As0 + (kt & 1) * ASZ;
        const bf16* BsB = Bs0 + (kt & 1) * BSZ;
#pragma unroll
        for (int k2 = 0; k2 < 2; ++k2) {
            bf16x8 af[FM], bfr[4];
#pragma unroll
            for (int i = 0; i < FM; ++i)
                af[i] = *(const bf16x8*)(AsB + (wm * WROWS + i * 16 + lr) * BK +
                                         (((k2 * 4 + quad) ^ swr) * 8));
#pragma unroll
            for (int j = 0; j < 4; ++j)
                bfr[j] = *(const bf16x8*)(BsB + (wn * 64 + j * 16 + lr) * BK +
                                          (((k2 * 4 + quad) ^ swr) * 8));
#pragma unroll
            for (int i = 0; i < FM; ++i)
#pragma unroll
                for (int j = 0; j < 4; ++j)
                    acc[i][j] = __builtin_amdgcn_mfma_f32_16x16x32_bf16(
                        af[i], bfr[j], acc[i][j], 0, 0, 0);
        }
        WAIT_VM(0);
        __syncthreads();
    }

    if constexpr (sizeof(OutT) == 2) {
        if (FUSE_VT && n0 >= 2048) {
            bf16* Cs = smem;
#pragma unroll
            for (int j = 0; j < 4; ++j) {
                int nl = wn * 64 + j * 16 + lr;
                float bv = bias[n0 + nl];
#pragma unroll
                for (int i = 0; i < FM; ++i) {
                    int ml = wm * WROWS + i * 16 + quad * 4;
#pragma unroll
                    for (int r = 0; r < 4; ++r)
                        Cs[nl * TST + ml + r] = (bf16)(acc[i][j][r] + bv);
                }
            }
            __syncthreads();
            const int bb = m0 >> 11;
            const int tloc = m0 & 2047;
#pragma unroll
            for (int pp = 0; pp < 8; ++pp) {
                int dl = pp * 16 + (tid >> 4);
                int t0 = (tid & 15) * 8;
                bf16x8 v = *(const bf16x8*)(Cs + dl * TST + t0);
                *(bf16x8*)(VT + (size_t)(bb * 1024 + (n0 - 2048) + dl) * TSEQ +
                           tloc + t0) = v;
            }
            return;
        }
        bf16* Cs = smem;
#pragma unroll
        for (int j = 0; j < 4; ++j) {
            int nl = wn * 64 + j * 16 + lr;
            float bv = bias[n0 + nl];
#pragma unroll
            for (int i = 0; i < FM; ++i) {
                int ml = wm * WROWS + i * 16 + quad * 4;
#pragma unroll
                for (int r = 0; r < 4; ++r)
                    Cs[(ml + r) * BN + nl] = (bf16)(acc[i][j][r] + bv);
            }
        }
        __syncthreads();
        constexpr int LPR = BN / 8;
        constexpr int RPP = 256 / LPR;
        const int rr = tid / LPR, cc = (tid % LPR) * 8;
#pragma unroll
        for (int pp = 0; pp < 128 / RPP; ++pp) {
            int row = pp * RPP + rr;
            *(bf16x8*)(C + (size_t)(m0 + row) * ldc + n0 + cc) =
                *(const bf16x8*)(Cs + row * BN + cc);
        }
    } else {
        float* Cf = (float*)smem;
#pragma unroll
        for (int half = 0; half < 2; ++half) {
            if (((wm * WROWS) >> 6) == half) {
#pragma unroll
                for (int j = 0; j < 4; ++j) {
                    int nl = wn * 64 + j * 16 + lr;
                    float bv = bias[n0 + nl];
#pragma unroll
                    for (int i = 0; i < FM; ++i) {
                        int ml = wm * WROWS + i * 16 + quad * 4 - half * 64;
#pragma unroll
                        for (int r = 0; r < 4; ++r)
                            Cf[(ml + r) * BNP + nl] = acc[i][j][r] + bv;
                    }
                }
            }
            __syncthreads();
            constexpr int LPR = BN / 4;
            constexpr int RPP = 256 / LPR;
            const int rr = tid / LPR, cc = (tid % LPR) * 4;
#pragma unroll
            for (int pp = 0; pp < 64 / RPP; ++pp) {
                int row = pp * RPP + rr;
                *(f32x4*)(C + (size_t)(m0 + half * 64 + row) * ldc + n0 + cc) =
                    *(const f32x4*)(Cf + row * BNP + cc);
            }
            __syncthreads();
        }
    }
}

// ---------------------------------------------------------------- flash attn
// 8-WAVE PARITY-GROUP kernel (r15 structure, SPILL-FIXED): 512 blocks x 512
// threads; two 4-wave groups process chunk parities concurrently over the 4
// LDS buffers; fixed-max softmax partials merge in LDS (3-round epilogue).
// R15 POST-MORTEM: __launch_bounds__(512,4) clamped VGPR to 128 -> compiler
// spilled the dual f32x16 accumulator sets to scratch (VGPR_Count=64,
// WRITE_SIZE 8->69MB, FETCH 12->53MB, flash 96us). Fix: (512,2) restores the
// 256-VGPR budget (same per-wave register content as r11's 104-VGPR build);
// hardware then fits 4 waves/SIMD on its own (104<=128), LDS-limited to
// 2 blocks/CU x 8 waves = 16 waves/CU — the occupancy target without spills.
template <int KTN, bool MASKED>
__device__ __forceinline__ void tile_step(
    int kt0, int kc, int qabs,
    const bf16* __restrict__ Ksb, const bf16* __restrict__ Vsb,
    const bf16x8 qf[4], f32x16 oacc[2], float& lrow,
    int ln31, int hi, int sw)
{
    f32x16 st[KTN] = {};
    __builtin_amdgcn_s_setprio(1);
#pragma unroll
    for (int t = 0; t < KTN; ++t)
#pragma unroll
        for (int ks = 0; ks < 4; ++ks) {
            const bf16x8 ka = *(const bf16x8*)(
                Ksb + (ln31 + (kt0 + t) * 32) * 64 + (((2 * ks + hi) ^ sw) * 8));
            st[t] = __builtin_amdgcn_mfma_f32_32x32x16_bf16(ka, qf[ks], st[t], 0, 0, 0);
        }
    __builtin_amdgcn_s_setprio(0);

    const float scale2 = 0.18033688f; // 0.125 * log2(e)
    float rs = 0.f;
#pragma unroll
    for (int t = 0; t < KTN; ++t)
#pragma unroll
        for (int r = 0; r < 16; ++r) {
            float p = exp2f(fmaf(st[t][r], scale2, -24.0f));
            if (MASKED &&
                (kc + (kt0 + t) * 32 + (r & 3) + 8 * (r >> 2) + 4 * hi > qabs))
                p = 0.f;
            rs += p;
            st[t][r] = p;
        }
    rs += __shfl_xor(rs, 32);
    lrow += rs;

    __builtin_amdgcn_s_setprio(1);
#pragma unroll
    for (int t = 0; t < KTN; ++t)
#pragma unroll
        for (int s2 = 0; s2 < 2; ++s2) {
            const int bb = s2 * 8;
            unsigned c01 = cvtpk(st[t][bb + 0], st[t][bb + 1]);
            unsigned c23 = cvtpk(st[t][bb + 2], st[t][bb + 3]);
            unsigned c45 = cvtpk(st[t][bb + 4], st[t][bb + 5]);
            unsigned c67 = cvtpk(st[t][bb + 6], st[t][bb + 7]);
            asm("v_permlane32_swap_b32 %0, %1" : "+v"(c01), "+v"(c45));
            asm("v_permlane32_swap_b32 %0, %1" : "+v"(c23), "+v"(c67));
            int4v pw;
            pw[0] = (int)c01; pw[1] = (int)c23; pw[2] = (int)c45; pw[3] = (int)c67;
            const bf16x8 pa = __builtin_bit_cast(bf16x8, pw);
            const int ksg = (kt0 + t) * 2 + s2;
#pragma unroll
            for (int dblk = 0; dblk < 2; ++dblk) {
                const bf16x8 vb = *(const bf16x8*)(
                    Vsb + (dblk * 32 + ln31) * 64 + (((2 * ksg + hi) ^ sw) * 8));
                oacc[dblk] = __builtin_amdgcn_mfma_f32_32x32x16_bf16(
                    pa, vb, oacc[dblk], 0, 0, 0);
            }
        }
    __builtin_amdgcn_s_setprio(0);
}

__global__ __launch_bounds__(512, 2) void flash_attn(
    const bf16* __restrict__ QKV, const bf16* __restrict__ VT,
    bf16* __restrict__ O)
{
    __shared__ bf16 Ks[4][64 * 64];
    __shared__ bf16 Vs[4][64 * 64];
    const int tid = threadIdx.x;
    const int ln = tid & 63, w = tid >> 6;       // 8 waves
    const int grp = w >> 2, wl = w & 3;          // 2 parity groups x 4 waves
    const int ln31 = ln & 31, hi = ln >> 5, sw = ln & 7;
    const int wg = blockIdx.x;
    const int g = wg & 31, p = wg >> 5;          // g = 2h+b -> fixed XCD per (b,h)
    const int h = g >> 1, b = g & 1;
    const int q0A = p * 64, q0B = (31 - p) * 64;

    const bf16* Qb = QKV + (size_t)b * TSEQ * NQKV + h * DKH;
    const bf16* Kb = Qb + 1024;
    const bf16* VTb = VT + (size_t)(b * NHEAD + h) * DKH * TSEQ;

    const int q1 = (wl < 2 ? q0A : q0B) + (wl & 1) * 32 + ln31;
    const int q2 = q0B + (wl & 1) * 32 + ln31;

    bf16x8 qf1[4], qf2[4];
#pragma unroll
    for (int ks = 0; ks < 4; ++ks) {
        qf1[ks] = *(const bf16x8*)(Qb + (size_t)q1 * NQKV + ks * 16 + hi * 8);
        qf2[ks] = *(const bf16x8*)(Qb + (size_t)q2 * NQKV + ks * 16 + hi * 8);
    }
    WAIT_VM(0);   // qf complete before any DMA -> clean in-loop counts

    // staging within group: wl{0,1} -> K row-halves, wl{2,3} -> V row-halves
    const int srow = (wl & 1) * 32 + (ln >> 3);
    const int scol = ((ln & 7) ^ ((ln >> 3) & 7)) * 8;
    const bool stK = (wl < 2);
    auto stage = [&](int buf, int kc) {
        if (stK) {
            const bf16* g2 = Kb + (size_t)(kc + srow) * NQKV + scol;
            bf16* s = &Ks[buf][(wl & 1) * 32 * 64];
#pragma unroll
            for (int l = 0; l < 4; ++l)
                gll16(g2 + (size_t)(l * 8) * NQKV, s + l * 8 * 64);
        } else {
            const bf16* g2 = VTb + (size_t)srow * TSEQ + kc + scol;
            bf16* s = &Vs[buf][(wl & 1) * 32 * 64];
#pragma unroll
            for (int l = 0; l < 4; ++l)
                gll16(g2 + (size_t)(l * 8) * TSEQ, s + l * 8 * 64);
        }
    };

    f32x16 oacc1[2] = {}, oacc2[2] = {};
    float l1 = 0.f, l2 = 0.f;

    const int nld = 32 - p;    // shared stream length (17..32)

    auto do_chunk = [&](int c) {
        const int kc = c * 64;
        const bf16* K = Ks[c & 3];
        const bf16* V = Vs[c & 3];
        if (c <= p) {            // phase1: full 64-key chunk, own tile
            if (wl < 2 && c == p)
                tile_step<2, true >(0, kc, q1, K, V, qf1, oacc1, l1, ln31, hi, sw);
            else
                tile_step<2, false>(0, kc, q1, K, V, qf1, oacc1, l1, ln31, hi, sw);
        } else {                 // phase2: all 4 group-waves on B, key-split
            const int kt0 = wl >> 1;
            if (c == nld - 1)
                tile_step<1, true >(kt0, kc, q2, K, V, qf2, oacc2, l2, ln31, hi, sw);
            else
                tile_step<1, false>(kt0, kc, q2, K, V, qf2, oacc2, l2, ln31, hi, sw);
        }
    };

    // group g owns chunks with parity g; 2 buffers per parity (c&3)
    if (grp == 0) stage(0, 0);
    else          stage(1, 64);              // nld >= 17 always
    for (int c0 = 0; c0 < nld; c0 += 2) {
        const int c = c0 + grp;              // my group's chunk this iteration
        WAIT_VM(0);                          // my prefetched chunk landed
        __syncthreads();                     // both groups' buffers visible
        const int cn = c + 2;
        if (cn < nld) stage(cn & 3, cn * 64);
        if (c < nld) do_chunk(c);
    }
    WAIT_VM(0);
    __syncthreads();                         // before epilogue LDS reuse

    // ---- epilogue: 3-round LDS merge of the two groups' linear partials.
    float* base = (float*)&Ks[0][0];
    float* AO  = base;                  // [2][32*64] f32 = 16KB (Ks bufs 0-1)
    float* BO  = base + 4096;           // 16KB (Ks bufs 2-3)
    float* BO2 = (float*)&Vs[0][0];     // 16KB (Vs bufs 0-1)
    float* AL  = (float*)&Vs[2][0];     // 64 f32 (in Vs buf 2)
    float* BL  = AL + 64;
    float* BL2 = AL + 128;
    const int rg = wl & 1;

    // R1: group 1 deposits its partials
    if (grp == 1) {
        if (wl < 2) {
            float* dA = AO + rg * 2048;
            float* dB = BO2 + rg * 2048;
#pragma unroll
            for (int dblk = 0; dblk < 2; ++dblk)
#pragma unroll
                for (int r = 0; r < 16; ++r) {
                    int q = (r & 3) + 8 * (r >> 2) + 4 * hi;
                    dA[q * 64 + dblk * 32 + ln31] = oacc1[dblk][r];
                    dB[q * 64 + dblk * 32 + ln31] = oacc2[dblk][r];
                }
            if (ln < 32) { AL[rg * 32 + ln] = l1; BL2[rg * 32 + ln] = l2; }
        } else {
            float* dB = BO + rg * 2048;
#pragma unroll
            for (int dblk = 0; dblk < 2; ++dblk)
#pragma unroll
                for (int r = 0; r < 16; ++r) {
                    int q = (r & 3) + 8 * (r >> 2) + 4 * hi;
                    dB[q * 64 + dblk * 32 + ln31] = oacc1[dblk][r] + oacc2[dblk][r];
                }
            if (ln < 32) BL[rg * 32 + ln] = l1 + l2;
        }
    }
    __syncthreads();
    // R2: group 0 merges; wl<2 write final A rows and add B shares
    if (grp == 0) {
        if (wl < 2) {
            float* dB = BO2 + rg * 2048;
#pragma unroll
            for (int dblk = 0; dblk < 2; ++dblk)
#pragma unroll
                for (int r = 0; r < 16; ++r) {
                    int q = (r & 3) + 8 * (r >> 2) + 4 * hi;
                    dB[q * 64 + dblk * 32 + ln31] += oacc2[dblk][r];
                }
            if (ln < 32) BL2[rg * 32 + ln] += l2;
            const float* sA = AO + rg * 2048;
            float lt = l1 + AL[rg * 32 + ln31];
            const int qs = q0A + rg * 32;
#pragma unroll
            for (int r = 0; r < 16; ++r) {
                const int crow = (r & 3) + 8 * (r >> 2) + 4 * hi;
                const float inv = 1.0f / __shfl(lt, crow);
                const int row = qs + crow;
#pragma unroll
                for (int dblk = 0; dblk < 2; ++dblk)
                    O[(size_t)(b * TSEQ + row) * DMODEL + h * DKH + dblk * 32 + ln31] =
                        (bf16)((oacc1[dblk][r] +
                                sA[crow * 64 + dblk * 32 + ln31]) * inv);
            }
        } else {
            float* dB = BO + rg * 2048;
#pragma unroll
            for (int dblk = 0; dblk < 2; ++dblk)
#pragma unroll
                for (int r = 0; r < 16; ++r) {
                    int q = (r & 3) + 8 * (r >> 2) + 4 * hi;
                    dB[q * 64 + dblk * 32 + ln31] += oacc1[dblk][r] + oacc2[dblk][r];
                }
            if (ln < 32) BL[rg * 32 + ln] += l1 + l2;
        }
    }
    __syncthreads();
    // R3: group 0 wl>=2 write final B rows
    if (grp == 0 && wl >= 2) {
        const float* sB  = BO + rg * 2048;
        const float* sB2 = BO2 + rg * 2048;
        float lt = BL[rg * 32 + ln31] + BL2[rg * 32 + ln31];
        const int qs = q0B + rg * 32;
#pragma unroll
        for (int r = 0; r < 16; ++r) {
            const int crow = (r & 3) + 8 * (r >> 2) + 4 * hi;
            const float inv = 1.0f / __shfl(lt, crow);
            const int row = qs + crow;
#pragma unroll
            for (int dblk = 0; dblk < 2; ++dblk) {
                const int idx = crow * 64 + dblk * 32 + ln31;
                O[(size_t)(b * TSEQ + row) * DMODEL + h * DKH + dblk * 32 + ln31] =
                    (bf16)((sB[idx] + sB2[idx]) * inv);
            }
        }
    }
}

// ---------------------------------------------------------------- launch
extern "C" void kernel_launch(void* const* d_in, const int* in_sizes, int n_in,
                              void* d_out, int out_size, void* d_ws, size_t ws_size,
                              hipStream_t stream)
{
    const float* x  = (const float*)d_in[0];
    const float* Wq = (const float*)d_in[2];
    const float* bq = (const float*)d_in[3];
    const float* Wk = (const float*)d_in[4];
    const float* bk = (const float*)d_in[5];
    const float* Wv = (const float*)d_in[6];
    const float* bv = (const float*)d_in[7];
    const float* Wo = (const float*)d_in[8];
    const float* bo = (const float*)d_in[9];

    char* ws = (char*)d_ws;
    bf16* xb   = (bf16*)(ws);                   // 8 MB
    bf16* QKV  = (bf16*)(ws + (8u  << 20));     // 24 MB [4096][3072] (V third unused)
    bf16* VT   = (bf16*)(ws + (32u << 20));     // 8 MB, written by QKV-GEMM V blocks
    bf16* O    = (bf16*)(ws + (40u << 20));     // 8 MB
    bf16* WT   = (bf16*)(ws + (48u << 20));     // 8 MB
    float* wsBias = (float*)O;                  // 12 KB, consumed before flash writes O

    prep<<<PREP_GRID, 256, 0, stream>>>(x, Wq, Wk, Wv, Wo, bq, bk, bv,
                                        xb, WT, wsBias);

    gemm_bias_kernel<bf16, 2, true><<<768, 256, 0, stream>>>(
        xb, WT, wsBias, QKV, NQKV, VT);

    flash_attn<<<512, 512, 0, stream>>>(QKV, VT, O);

    gemm_bias_kernel<float, 1, false><<<512, 256, 0, stream>>>(
        O, WT + 3u * (1u << 20), bo, (float*)d_out, DMODEL, nullptr);
}

// Round 17
// 198.701 us; speedup vs baseline: 1.2904x; 1.0485x over previous
//
#include <hip/hip_runtime.h>
#include <hip/hip_bf16.h>

typedef __bf16 bf16;
typedef __attribute__((ext_vector_type(8))) __bf16 bf16x8;
typedef __attribute__((ext_vector_type(4))) __bf16 bf16x4;
typedef __attribute__((ext_vector_type(4))) float f32x4;
typedef __attribute__((ext_vector_type(16))) float f32x16;
typedef __attribute__((ext_vector_type(4))) int int4v;

#define TSEQ 2048
#define DMODEL 1024
#define NHEAD 16
#define DKH 64
#define BATCH 2
#define NQKV 3072

// async global->LDS, 16B per lane; LDS dest = wave-uniform base + lane*16
typedef __attribute__((address_space(1))) const void gv_t;
typedef __attribute__((address_space(3))) void sv_t;
__device__ __forceinline__ void gll16(const bf16* g, bf16* s) {
    __builtin_amdgcn_global_load_lds((gv_t*)g, (sv_t*)s, 16, 0, 0);
}
// counted vmcnt wait (lgkmcnt=15, expcnt=7 untouched). __syncthreads does NOT
// drain DMA vmcnt on this toolchain -> explicit wait required.
#define WAIT_VM(n) __builtin_amdgcn_s_waitcnt(0x0F70 | (n))

// v_cvt_pk_bf16_f32: D.lo = bf16(s0), D.hi = bf16(s1)
__device__ __forceinline__ unsigned cvtpk(float lo, float hi) {
    unsigned d;
    asm("v_cvt_pk_bf16_f32 %0, %1, %2" : "=v"(d) : "v"(lo), "v"(hi));
    return d;
}

// ------------------------------------------------------- fused prep kernel
#define PREP_CONV 4096   // NX / (256*4)
#define PREP_TW   4096
#define PREP_GRID (PREP_CONV + PREP_TW + 12)
__global__ __launch_bounds__(256) void prep(
    const float* __restrict__ x,
    const float* __restrict__ Wq, const float* __restrict__ Wk,
    const float* __restrict__ Wv, const float* __restrict__ Wo,
    const float* __restrict__ bq, const float* __restrict__ bk,
    const float* __restrict__ bv,
    bf16* __restrict__ xb, bf16* __restrict__ WT, float* __restrict__ biasO)
{
    __shared__ float t[32][33];
    int bid = blockIdx.x;
    const int tid = threadIdx.x;
    if (bid < PREP_CONV) {                       // ---- convert
        int i = (bid * 256 + tid) * 4;
        f32x4 v = *(const f32x4*)(x + i);
        bf16x4 o;
#pragma unroll
        for (int j = 0; j < 4; ++j) o[j] = (bf16)v[j];
        *(bf16x4*)(xb + i) = o;
        return;
    }
    bid -= PREP_CONV;
    if (bid < PREP_TW) {                         // ---- transpose W (32x32 tile)
        int z = bid >> 10;
        int by = ((bid >> 5) & 31) * 32, bx = (bid & 31) * 32;
        const float* W = z == 0 ? Wq : z == 1 ? Wk : z == 2 ? Wv : Wo;
        bf16* T = WT + (size_t)z * DMODEL * DMODEL;
        int tx = tid & 31, ty = tid >> 5;
#pragma unroll
        for (int i = 0; i < 4; ++i)
            t[ty + i * 8][tx] = W[(size_t)(by + ty + i * 8) * DMODEL + bx + tx];
        __syncthreads();
#pragma unroll
        for (int i = 0; i < 4; ++i)
            T[(size_t)(bx + ty + i * 8) * DMODEL + by + tx] = (bf16)t[tx][ty + i * 8];
        return;
    }
    bid -= PREP_TW;
    int i = bid * 256 + tid;                     // ---- bias concat, 0..3071
    float v = i < 1024 ? bq[i] : i < 2048 ? bk[i - 1024] : bv[i - 2048];
    biasO[i] = v;
}

// ---------------------------------------------------------------- GEMM + bias
// (r11 body, proven) BK=64, 2-buffer, XOR-swizzled LDS tiles, XCD-chunked
// mapping. FUSE_VT: n0>=2048 writes V-part transposed to VT.
template <typename OutT, int NW_N, bool FUSE_VT>
__global__ __launch_bounds__(256) void gemm_bias_kernel(
    const bf16* __restrict__ A, const bf16* __restrict__ BT,
    const float* __restrict__ bias, OutT* __restrict__ C, int ldc,
    bf16* __restrict__ VT)
{
    constexpr int BN    = NW_N * 64;
    constexpr int MW    = 4 / NW_N;
    constexpr int WROWS = 128 / MW;
    constexpr int FM    = WROWS / 16;
    constexpr int BK    = 64;
    constexpr int ASZ   = 128 * BK;
    constexpr int BSZ   = BN * BK;
    constexpr int BNP   = BN + 4;
    constexpr int TST   = 136;
    constexpr int EPI   = sizeof(OutT) == 2 ? (FUSE_VT ? 128 * TST : 128 * BN)
                                            : 64 * BNP * 2;
    constexpr int STG   = 2 * ASZ + 2 * BSZ;
    constexpr int SMEM  = STG > EPI ? STG : EPI;
    __shared__ bf16 smem[SMEM];
    bf16* As0 = smem;
    bf16* Bs0 = smem + 2 * ASZ;

    const int tid = threadIdx.x;
    const int ln = tid & 63, wave = tid >> 6;
    const int wm = NW_N == 2 ? (wave >> 1) : wave;
    const int wn = NW_N == 2 ? (wave & 1) : 0;
    const int lr = ln & 15, quad = ln >> 4;

    constexpr int NBX = (NW_N == 2) ? 24 : 16;
    constexpr int CH  = (NW_N == 2) ? 96 : 64;
    const int wg  = blockIdx.x;
    const int lin = (wg & 7) * CH + (wg >> 3);
    const int m0  = (lin / NBX) * 128, n0 = (lin % NBX) * BN;

    f32x4 acc[FM][4] = {};

    const int srow = ln >> 3;
    const int scol = ((ln & 7) ^ srow) * 8;
    const bf16* Ag = A + (size_t)(m0 + wave * 32 + srow) * DMODEL + scol;
    const bf16* Bg = BT + (size_t)(n0 + (NW_N == 2 ? wave * 32 : wave * 16) + srow) * DMODEL + scol;

    auto stage = [&](int buf, int kk) {
        bf16* AsW = As0 + buf * ASZ + wave * (32 * BK);
#pragma unroll
        for (int l = 0; l < 4; ++l)
            gll16(Ag + (size_t)(l * 8) * DMODEL + kk, AsW + l * 8 * BK);
        if constexpr (NW_N == 2) {
            bf16* BsW = Bs0 + buf * BSZ + wave * (32 * BK);
#pragma unroll
            for (int l = 0; l < 4; ++l)
                gll16(Bg + (size_t)(l * 8) * DMODEL + kk, BsW + l * 8 * BK);
        } else {
            bf16* BsW = Bs0 + buf * BSZ + wave * (16 * BK);
#pragma unroll
            for (int l = 0; l < 2; ++l)
                gll16(Bg + (size_t)(l * 8) * DMODEL + kk, BsW + l * 8 * BK);
        }
    };

    constexpr int NT = DMODEL / BK;
    stage(0, 0);
    WAIT_VM(0);
    __syncthreads();
    const int swr = lr & 7;
    for (int kt = 0; kt < NT; ++kt) {
        if (kt + 1 < NT) stage((kt + 1) & 1, (kt + 1) * BK);
        const bf16* AsB = As0 + (kt & 1) * ASZ;
        const bf16* BsB = Bs0 + (kt & 1) * BSZ;
#pragma unroll
        for (int k2 = 0; k2 < 2; ++k2) {
            bf16x8 af[FM], bfr[4];
#pragma unroll
            for (int i = 0; i < FM; ++i)
                af[i] = *(const bf16x8*)(AsB + (wm * WROWS + i * 16 + lr) * BK +
                                         (((k2 * 4 + quad) ^ swr) * 8));
#pragma unroll
            for (int j = 0; j < 4; ++j)
                bfr[j] = *(const bf16x8*)(BsB + (wn * 64 + j * 16 + lr) * BK +
                                          (((k2 * 4 + quad) ^ swr) * 8));
#pragma unroll
            for (int i = 0; i < FM; ++i)
#pragma unroll
                for (int j = 0; j < 4; ++j)
                    acc[i][j] = __builtin_amdgcn_mfma_f32_16x16x32_bf16(
                        af[i], bfr[j], acc[i][j], 0, 0, 0);
        }
        WAIT_VM(0);
        __syncthreads();
    }

    if constexpr (sizeof(OutT) == 2) {
        if (FUSE_VT && n0 >= 2048) {
            bf16* Cs = smem;
#pragma unroll
            for (int j = 0; j < 4; ++j) {
                int nl = wn * 64 + j * 16 + lr;
                float bv = bias[n0 + nl];
#pragma unroll
                for (int i = 0; i < FM; ++i) {
                    int ml = wm * WROWS + i * 16 + quad * 4;
#pragma unroll
                    for (int r = 0; r < 4; ++r)
                        Cs[nl * TST + ml + r] = (bf16)(acc[i][j][r] + bv);
                }
            }
            __syncthreads();
            const int bb = m0 >> 11;
            const int tloc = m0 & 2047;
#pragma unroll
            for (int pp = 0; pp < 8; ++pp) {
                int dl = pp * 16 + (tid >> 4);
                int t0 = (tid & 15) * 8;
                bf16x8 v = *(const bf16x8*)(Cs + dl * TST + t0);
                *(bf16x8*)(VT + (size_t)(bb * 1024 + (n0 - 2048) + dl) * TSEQ +
                           tloc + t0) = v;
            }
            return;
        }
        bf16* Cs = smem;
#pragma unroll
        for (int j = 0; j < 4; ++j) {
            int nl = wn * 64 + j * 16 + lr;
            float bv = bias[n0 + nl];
#pragma unroll
            for (int i = 0; i < FM; ++i) {
                int ml = wm * WROWS + i * 16 + quad * 4;
#pragma unroll
                for (int r = 0; r < 4; ++r)
                    Cs[(ml + r) * BN + nl] = (bf16)(acc[i][j][r] + bv);
            }
        }
        __syncthreads();
        constexpr int LPR = BN / 8;
        constexpr int RPP = 256 / LPR;
        const int rr = tid / LPR, cc = (tid % LPR) * 8;
#pragma unroll
        for (int pp = 0; pp < 128 / RPP; ++pp) {
            int row = pp * RPP + rr;
            *(bf16x8*)(C + (size_t)(m0 + row) * ldc + n0 + cc) =
                *(const bf16x8*)(Cs + row * BN + cc);
        }
    } else {
        float* Cf = (float*)smem;
#pragma unroll
        for (int half = 0; half < 2; ++half) {
            if (((wm * WROWS) >> 6) == half) {
#pragma unroll
                for (int j = 0; j < 4; ++j) {
                    int nl = wn * 64 + j * 16 + lr;
                    float bv = bias[n0 + nl];
#pragma unroll
                    for (int i = 0; i < FM; ++i) {
                        int ml = wm * WROWS + i * 16 + quad * 4 - half * 64;
#pragma unroll
                        for (int r = 0; r < 4; ++r)
                            Cf[(ml + r) * BNP + nl] = acc[i][j][r] + bv;
                    }
                }
            }
            __syncthreads();
            constexpr int LPR = BN / 4;
            constexpr int RPP = 256 / LPR;
            const int rr = tid / LPR, cc = (tid % LPR) * 4;
#pragma unroll
            for (int pp = 0; pp < 64 / RPP; ++pp) {
                int row = pp * RPP + rr;
                *(f32x4*)(C + (size_t)(m0 + half * 64 + row) * ldc + n0 + cc) =
                    *(const f32x4*)(Cf + row * BNP + cc);
            }
            __syncthreads();
        }
    }
}

// ---------------------------------------------------------------- flash attn
// (r7/r11-proven, best-known) 32x32x16 swapped-QK^T, softmax fully
// in-register (fixed-max M=24 exp2 domain; shift-invariant), P->A-frag via
// cvt_pk + v_permlane32_swap_b32, paired tiles A=p/B=31-p sharing one K/V
// stream (uniform work), 2 chunks per iteration over 4 LDS buffers with the
// wait-before-issue counted-vmcnt shell.
// PLATEAU NOTE (r4-r16): nine structural variants (pipeline depth, split-K,
// block granularity, 8-wave parity groups) all land at 45-96us; wave-supply
// is refuted as the limiter (r16: 2x waves, same time). This 4-wave config
// is the best measured; do not restructure without a new mechanism.
template <int KTN, bool MASKED>
__device__ __forceinline__ void tile_step(
    int kt0, int kc, int qabs,
    const bf16* __restrict__ Ksb, const bf16* __restrict__ Vsb,
    const bf16x8 qf[4], f32x16 oacc[2], float& lrow,
    int ln31, int hi, int sw)
{
    f32x16 st[KTN] = {};
    __builtin_amdgcn_s_setprio(1);
#pragma unroll
    for (int t = 0; t < KTN; ++t)
#pragma unroll
        for (int ks = 0; ks < 4; ++ks) {
            const bf16x8 ka = *(const bf16x8*)(
                Ksb + (ln31 + (kt0 + t) * 32) * 64 + (((2 * ks + hi) ^ sw) * 8));
            st[t] = __builtin_amdgcn_mfma_f32_32x32x16_bf16(ka, qf[ks], st[t], 0, 0, 0);
        }
    __builtin_amdgcn_s_setprio(0);

    const float scale2 = 0.18033688f; // 0.125 * log2(e)
    float rs = 0.f;
#pragma unroll
    for (int t = 0; t < KTN; ++t)
#pragma unroll
        for (int r = 0; r < 16; ++r) {
            float p = exp2f(fmaf(st[t][r], scale2, -24.0f));
            if (MASKED &&
                (kc + (kt0 + t) * 32 + (r & 3) + 8 * (r >> 2) + 4 * hi > qabs))
                p = 0.f;
            rs += p;
            st[t][r] = p;
        }
    rs += __shfl_xor(rs, 32);
    lrow += rs;

    __builtin_amdgcn_s_setprio(1);
#pragma unroll
    for (int t = 0; t < KTN; ++t)
#pragma unroll
        for (int s2 = 0; s2 < 2; ++s2) {
            const int bb = s2 * 8;
            unsigned c01 = cvtpk(st[t][bb + 0], st[t][bb + 1]);
            unsigned c23 = cvtpk(st[t][bb + 2], st[t][bb + 3]);
            unsigned c45 = cvtpk(st[t][bb + 4], st[t][bb + 5]);
            unsigned c67 = cvtpk(st[t][bb + 6], st[t][bb + 7]);
            asm("v_permlane32_swap_b32 %0, %1" : "+v"(c01), "+v"(c45));
            asm("v_permlane32_swap_b32 %0, %1" : "+v"(c23), "+v"(c67));
            int4v pw;
            pw[0] = (int)c01; pw[1] = (int)c23; pw[2] = (int)c45; pw[3] = (int)c67;
            const bf16x8 pa = __builtin_bit_cast(bf16x8, pw);
            const int ksg = (kt0 + t) * 2 + s2;
#pragma unroll
            for (int dblk = 0; dblk < 2; ++dblk) {
                const bf16x8 vb = *(const bf16x8*)(
                    Vsb + (dblk * 32 + ln31) * 64 + (((2 * ksg + hi) ^ sw) * 8));
                oacc[dblk] = __builtin_amdgcn_mfma_f32_32x32x16_bf16(
                    pa, vb, oacc[dblk], 0, 0, 0);
            }
        }
    __builtin_amdgcn_s_setprio(0);
}

__global__ __launch_bounds__(256, 2) void flash_attn(
    const bf16* __restrict__ QKV, const bf16* __restrict__ VT,
    bf16* __restrict__ O)
{
    __shared__ bf16 Ks[4][64 * 64];
    __shared__ bf16 Vs[4][64 * 64];
    const int tid = threadIdx.x;
    const int ln = tid & 63, w = tid >> 6;       // 4 waves
    const int ln31 = ln & 31, hi = ln >> 5, sw = ln & 7;
    const int wg = blockIdx.x;
    const int g = wg & 31, p = wg >> 5;          // g = 2h+b -> fixed XCD per (b,h)
    const int h = g >> 1, b = g & 1;
    const int q0A = p * 64, q0B = (31 - p) * 64;

    const bf16* Qb = QKV + (size_t)b * TSEQ * NQKV + h * DKH;
    const bf16* Kb = Qb + 1024;
    const bf16* VTb = VT + (size_t)(b * NHEAD + h) * DKH * TSEQ;

    const int q1 = (w < 2 ? q0A : q0B) + (w & 1) * 32 + ln31;
    const int q2 = q0B + (w & 1) * 32 + ln31;

    bf16x8 qf1[4], qf2[4];
#pragma unroll
    for (int ks = 0; ks < 4; ++ks) {
        qf1[ks] = *(const bf16x8*)(Qb + (size_t)q1 * NQKV + ks * 16 + hi * 8);
        qf2[ks] = *(const bf16x8*)(Qb + (size_t)q2 * NQKV + ks * 16 + hi * 8);
    }
    WAIT_VM(0);   // qf complete before any DMA -> clean in-loop counts

    const int srow = (w & 1) * 32 + (ln >> 3);
    const int scol = ((ln & 7) ^ ((ln >> 3) & 7)) * 8;
    const bool stK = (w < 2);
    auto stage = [&](int buf, int kc) {
        if (stK) {
            const bf16* g2 = Kb + (size_t)(kc + srow) * NQKV + scol;
            bf16* s = &Ks[buf][(w & 1) * 32 * 64];
#pragma unroll
            for (int l = 0; l < 4; ++l)
                gll16(g2 + (size_t)(l * 8) * NQKV, s + l * 8 * 64);
        } else {
            const bf16* g2 = VTb + (size_t)srow * TSEQ + kc + scol;
            bf16* s = &Vs[buf][(w & 1) * 32 * 64];
#pragma unroll
            for (int l = 0; l < 4; ++l)
                gll16(g2 + (size_t)(l * 8) * TSEQ, s + l * 8 * 64);
        }
    };

    f32x16 oacc1[2] = {}, oacc2[2] = {};
    float l1 = 0.f, l2 = 0.f;

    const int nld = 32 - p;    // shared stream length (17..32)

    auto do_chunk = [&](int c) {
        const int kc = c * 64;
        const bf16* K = Ks[c & 3];
        const bf16* V = Vs[c & 3];
        if (c <= p) {            // phase1: full 64-key chunk, own tile
            if (w < 2 && c == p)
                tile_step<2, true >(0, kc, q1, K, V, qf1, oacc1, l1, ln31, hi, sw);
            else
                tile_step<2, false>(0, kc, q1, K, V, qf1, oacc1, l1, ln31, hi, sw);
        } else {                 // phase2: all waves on B, key-split
            const int kt0 = w >> 1;
            if (c == nld - 1)
                tile_step<1, true >(kt0, kc, q2, K, V, qf2, oacc2, l2, ln31, hi, sw);
            else
                tile_step<1, false>(kt0, kc, q2, K, V, qf2, oacc2, l2, ln31, hi, sw);
        }
    };

    stage(0, 0);
    stage(1, 64);              // nld >= 17 always
    for (int c = 0; c < nld; c += 2) {
        WAIT_VM(0);            // pair (c,c+1) landed; nothing newer in flight
        __syncthreads();       // collective visibility + prev computes done
        if (c + 2 < nld) stage((c + 2) & 3, (c + 2) * 64);
        if (c + 3 < nld) stage((c + 3) & 3, (c + 3) * 64);
        do_chunk(c);
        if (c + 1 < nld) do_chunk(c + 1);
    }
    __syncthreads();           // before epilogue LDS reuse

    // ---- epilogue: combine phase2 partials (w0->w2, w1->w3) via LDS
    float* exO = (float*)&Ks[0][0];   // 2 x 32q x 64d f32 = 16KB
    float* exL = (float*)&Vs[0][0];   // 2 x 32 f32
    if (w < 2) {
        float* dst = exO + w * 2048;
#pragma unroll
        for (int dblk = 0; dblk < 2; ++dblk)
#pragma unroll
            for (int r = 0; r < 16; ++r) {
                int q = (r & 3) + 8 * (r >> 2) + 4 * hi;
                dst[q * 64 + dblk * 32 + ln31] = oacc2[dblk][r];
            }
        if (ln < 32) exL[w * 32 + ln] = l2;
    }
    __syncthreads();

    f32x16 oat[2];
    float lt;
    int qs;
    if (w < 2) {
        oat[0] = oacc1[0]; oat[1] = oacc1[1];
        lt = l1;
        qs = q0A + (w & 1) * 32;
    } else {
        const float* src = exO + (w - 2) * 2048;
        lt = l1 + l2 + exL[(w - 2) * 32 + ln31];
#pragma unroll
        for (int dblk = 0; dblk < 2; ++dblk)
#pragma unroll
            for (int r = 0; r < 16; ++r) {
                int q = (r & 3) + 8 * (r >> 2) + 4 * hi;
                oat[dblk][r] = oacc1[dblk][r] + oacc2[dblk][r] +
                               src[q * 64 + dblk * 32 + ln31];
            }
        qs = q0B + (w & 1) * 32;
    }

#pragma unroll
    for (int r = 0; r < 16; ++r) {
        const int crow = (r & 3) + 8 * (r >> 2) + 4 * hi;
        const float inv = 1.0f / __shfl(lt, crow);
        const int row = qs + crow;
#pragma unroll
        for (int dblk = 0; dblk < 2; ++dblk)
            O[(size_t)(b * TSEQ + row) * DMODEL + h * DKH + dblk * 32 + ln31] =
                (bf16)(oat[dblk][r] * inv);
    }
}

// ---------------------------------------------------------------- launch
extern "C" void kernel_launch(void* const* d_in, const int* in_sizes, int n_in,
                              void* d_out, int out_size, void* d_ws, size_t ws_size,
                              hipStream_t stream)
{
    const float* x  = (const float*)d_in[0];
    const float* Wq = (const float*)d_in[2];
    const float* bq = (const float*)d_in[3];
    const float* Wk = (const float*)d_in[4];
    const float* bk = (const float*)d_in[5];
    const float* Wv = (const float*)d_in[6];
    const float* bv = (const float*)d_in[7];
    const float* Wo = (const float*)d_in[8];
    const float* bo = (const float*)d_in[9];

    char* ws = (char*)d_ws;
    bf16* xb   = (bf16*)(ws);                   // 8 MB
    bf16* QKV  = (bf16*)(ws + (8u  << 20));     // 24 MB [4096][3072] (V third unused)
    bf16* VT   = (bf16*)(ws + (32u << 20));     // 8 MB, written by QKV-GEMM V blocks
    bf16* O    = (bf16*)(ws + (40u << 20));     // 8 MB
    bf16* WT   = (bf16*)(ws + (48u << 20));     // 8 MB
    float* wsBias = (float*)O;                  // 12 KB, consumed before flash writes O

    prep<<<PREP_GRID, 256, 0, stream>>>(x, Wq, Wk, Wv, Wo, bq, bk, bv,
                                        xb, WT, wsBias);

    gemm_bias_kernel<bf16, 2, true><<<768, 256, 0, stream>>>(
        xb, WT, wsBias, QKV, NQKV, VT);

    flash_attn<<<512, 256, 0, stream>>>(QKV, VT, O);

    gemm_bias_kernel<float, 1, false><<<512, 256, 0, stream>>>(
        O, WT + 3u * (1u << 20), bo, (float*)d_out, DMODEL, nullptr);
}